// Round 7
// baseline (47.626 us; speedup 1.0000x reference)
//
#include <hip/hip_runtime.h>

#define TT 1024
#define FF 512
#define BB 32
#define MAXSEG 513   // valleys are never adjacent -> cnt <= 512
#define GRP 4        // segments per wave
#define GPB (TT / GRP)   // 256 groups per batch (sA >= cnt -> dead, incl. all s>=512)

typedef float f32x4 __attribute__((ext_vector_type(4)));

__device__ __forceinline__ void nt_store4(float* p, f32x4 v) {
    __builtin_nontemporal_store(v, (f32x4*)p);
}

// ---------------- Kernel 1: ws[b,t] = sigmoid(x[b,t,:] . w + bias) ----------
// One wave per row; lane i handles 8 contiguous floats. Double accumulation:
// closest-to-exact dot -> minimizes strict-< valley tie flips vs numpy ref.
__global__ __launch_bounds__(256) void gate_kernel(const float* __restrict__ x,
                                                   const float* __restrict__ w,
                                                   const float* __restrict__ bias,
                                                   float* __restrict__ ws) {
    int wid  = threadIdx.x >> 6;
    int lane = threadIdx.x & 63;
    int row  = blockIdx.x * 4 + wid;              // 0 .. 32767
    const float4* xr = (const float4*)(x + (size_t)row * FF);
    const float4* wr = (const float4*)w;
    float4 x0 = xr[lane * 2],     x1 = xr[lane * 2 + 1];
    float4 w0 = wr[lane * 2],     w1 = wr[lane * 2 + 1];
    double acc = (double)x0.x * w0.x + (double)x0.y * w0.y +
                 (double)x0.z * w0.z + (double)x0.w * w0.w +
                 (double)x1.x * w1.x + (double)x1.y * w1.y +
                 (double)x1.z * w1.z + (double)x1.w * w1.w;
    #pragma unroll
    for (int off = 32; off; off >>= 1) acc += __shfl_down(acc, off);
    if (lane == 0) {
        float z = (float)acc + bias[0];
        ws[row] = 1.0f / (1.0f + expf(-z));
    }
}

// ---------------- Kernel 2: per-batch valley detect + segment build ---------
// (unchanged from R4/R5 passing versions)
__global__ __launch_bounds__(1024) void seg_kernel(const float* __restrict__ ws,
                                                   int* __restrict__ seg_start,
                                                   int* __restrict__ seg_end,
                                                   float* __restrict__ den,
                                                   int* __restrict__ counts) {
    int b = blockIdx.x, t = threadIdx.x;
    __shared__ float w[TT];
    __shared__ float p[TT];
    __shared__ unsigned long long words[16];
    __shared__ float wavesum[16];
    __shared__ int sst[MAXSEG];
    __shared__ int sen[MAXSEG];

    w[t] = ws[b * TT + t];
    __syncthreads();

    float wt = w[t];
    bool valley = (t > 0) && (t < TT - 1) && (wt < w[t - 1]) && (wt < w[t + 1]);
    unsigned long long m = __ballot(valley);
    int wid = t >> 6, lane = t & 63;
    if (lane == 0) words[wid] = m;

    float s = wt;
    #pragma unroll
    for (int off = 1; off < 64; off <<= 1) {
        float v = __shfl_up(s, off);
        if (lane >= off) s += v;
    }
    if (lane == 63) wavesum[wid] = s;
    __syncthreads();

    float offset = 0.0f;
    for (int i = 0; i < wid; ++i) offset += wavesum[i];
    p[t] = s + offset;                     // inclusive prefix over the row

    int before = __popcll(m & ((1ull << lane) - 1ull));
    int total = 0;
    for (int i = 0; i < 16; ++i) {
        int pc = __popcll(words[i]);
        if (i < wid) before += pc;
        total += pc;
    }
    if (valley) {
        int en = t + 2; if (en > TT) en = TT;
        sst[before + 1] = t;               // start of segment rank+1
        sen[before]     = en;              // end of segment rank
    }
    if (t == 0) {
        sst[0]     = 0;
        sen[total] = TT;
        counts[b]  = total + 1;
    }
    __syncthreads();

    int cnt = total + 1;
    if (t < cnt) {
        int st = sst[t], en = sen[t];
        seg_start[b * TT + t] = st;
        seg_end  [b * TT + t] = en;
        float d = p[en - 1] - (st > 0 ? p[st - 1] : 0.0f);
        den[b * TT + t] = fmaxf(d, 1e-6f);
    }
}

// ---- Kernel 3: grouped segment means (+ mask) ------------------------------
// One wave = 4 consecutive segments of one batch, streamed once over their
// t-range. Consecutive segments overlap by EXACTLY rows {t-1, t} at the emit
// row t (segment len >= 2, valleys >= 2 apart), so a single accumulator plus
// a 2-row (prev row, prev weight) history suffices: on emit, re-init
// acc = w[t-1]*x[t-1] + w[t]*x[t]. A while-loop handles the one tie case
// (last valley at T-2 -> last two segments both end at T). 4-row load blocks
// keep 8 independent 16B loads in flight per wave.
__global__ __launch_bounds__(256) void out_kernel(const float* __restrict__ x,
                                                  const float* __restrict__ ws,
                                                  const int* __restrict__ seg_start,
                                                  const int* __restrict__ seg_end,
                                                  const float* __restrict__ den,
                                                  const int* __restrict__ counts,
                                                  const int* __restrict__ seq,
                                                  float* __restrict__ out) {
    int bid = blockIdx.x;

    // ---- fused new_mask: 32 designated blocks write the [B,T] mask
    if ((bid & 63) == 0) {
        int bb = bid >> 6;
        int maxc = 0;
        #pragma unroll
        for (int i = 0; i < BB; ++i) maxc = max(maxc, counts[i]);
        float l0 = (float)seq[0];
        float v  = ((float)seq[bb] / l0) * (float)maxc;   // match jnp f32 order
        int nl = (int)v;                                  // trunc like astype
        float* mrow = out + (size_t)BB * TT * FF + (size_t)bb * TT;
        int s4 = threadIdx.x * 4;
        f32x4 mv;
        mv.x = (s4 + 0 < nl) ? 1.0f : 0.0f;
        mv.y = (s4 + 1 < nl) ? 1.0f : 0.0f;
        mv.z = (s4 + 2 < nl) ? 1.0f : 0.0f;
        mv.w = (s4 + 3 < nl) ? 1.0f : 0.0f;
        nt_store4(mrow + s4, mv);
    }

    // XCD swizzle: 2048 blocks -> XCD k owns 4 contiguous batches.
    int swz = (bid & 7) * 256 + (bid >> 3);
    int wid  = threadIdx.x >> 6;
    int lane = threadIdx.x & 63;
    int gid = swz * 4 + wid;              // 0 .. 8191
    int b   = gid >> 8;                   // /GPB
    int g   = gid & (GPB - 1);
    int cnt = counts[b];
    int sA  = g * GRP;
    float* obase = out + ((size_t)b * TT + sA) * FF + lane * 8;

    int live = cnt - sA;
    if (live > GRP) live = GRP;
    if (live < 0)  live = 0;
    f32x4 z = 0.0f;
    for (int k = live; k < GRP; ++k) {    // dead rows of this group
        nt_store4(obase + (size_t)k * FF,     z);
        nt_store4(obase + (size_t)k * FF + 4, z);
    }
    if (live == 0) return;

    int sEnd = sA + live;
    const int*   sstB = seg_start + b * TT;
    const int*   senB = seg_end   + b * TT;
    const float* denB = den       + b * TT;
    const float* wsr  = ws        + b * TT;
    const float* xb   = x + (size_t)b * TT * FF + lane * 8;

    int curSeg = sA;
    int curEnd = senB[curSeg];
    int t0 = sstB[sA];
    int t1 = senB[sEnd - 1];

    f32x4 a0 = 0.0f, a1 = 0.0f;           // current segment accumulator
    f32x4 p0 = 0.0f, p1 = 0.0f;           // previous row (history)
    float wp = 0.0f;

    for (int t = t0; t < t1; t += 4) {
        // issue all 8 loads of the 4-row block up front (clamped; L1-hits)
        int ta = t;
        int tb = (t + 1 < t1) ? t + 1 : t1 - 1;
        int tc = (t + 2 < t1) ? t + 2 : t1 - 1;
        int td = (t + 3 < t1) ? t + 3 : t1 - 1;
        const f32x4* qa = (const f32x4*)(xb + (size_t)ta * FF);
        const f32x4* qb = (const f32x4*)(xb + (size_t)tb * FF);
        const f32x4* qc = (const f32x4*)(xb + (size_t)tc * FF);
        const f32x4* qd = (const f32x4*)(xb + (size_t)td * FF);
        f32x4 ra0 = qa[0], ra1 = qa[1];
        f32x4 rb0 = qb[0], rb1 = qb[1];
        f32x4 rc0 = qc[0], rc1 = qc[1];
        f32x4 rd0 = qd[0], rd1 = qd[1];

        #pragma unroll
        for (int k = 0; k < 4; ++k) {
            int tk = t + k;
            if (tk >= t1) break;
            f32x4 r0 = (k == 0) ? ra0 : (k == 1) ? rb0 : (k == 2) ? rc0 : rd0;
            f32x4 r1 = (k == 0) ? ra1 : (k == 1) ? rb1 : (k == 2) ? rc1 : rd1;
            float wv = wsr[tk];
            a0 += wv * r0;
            a1 += wv * r1;
            while (tk == curEnd - 1) {     // emit (while: handles the T-tie)
                float inv = 1.0f / denB[curSeg];
                nt_store4(obase + (size_t)(curSeg - sA) * FF,     a0 * inv);
                nt_store4(obase + (size_t)(curSeg - sA) * FF + 4, a1 * inv);
                ++curSeg;
                if (curSeg >= sEnd) { curEnd = 0x7fffffff; break; }
                // next segment starts at rows {tk-1, tk}: rebuild from history
                a0 = wp * p0 + wv * r0;
                a1 = wp * p1 + wv * r1;
                curEnd = senB[curSeg];
            }
            p0 = r0; p1 = r1; wp = wv;
        }
    }
}

extern "C" void kernel_launch(void* const* d_in, const int* in_sizes, int n_in,
                              void* d_out, int out_size, void* d_ws, size_t ws_size,
                              hipStream_t stream) {
    const float* x    = (const float*)d_in[0];
    const float* aw   = (const float*)d_in[1];
    const float* ab   = (const float*)d_in[2];
    const int*   seq  = (const int*)d_in[3];
    float* out = (float*)d_out;

    // workspace layout (floats): ws[32768] | den[32768] | sstart[32768] |
    //                            send[32768] | counts[32]
    float* ws     = (float*)d_ws;
    float* den    = ws + BB * TT;
    int*   sstart = (int*)(ws + 2 * BB * TT);
    int*   send   = (int*)(ws + 3 * BB * TT);
    int*   counts = (int*)(ws + 4 * BB * TT);

    gate_kernel<<<BB * TT / 4, 256, 0, stream>>>(x, aw, ab, ws);
    seg_kernel<<<BB, 1024, 0, stream>>>(ws, sstart, send, den, counts);
    out_kernel<<<2048, 256, 0, stream>>>(x, ws, sstart, send, den, counts,
                                         seq, out);
}